// Round 1
// baseline (84.719 us; speedup 1.0000x reference)
//
#include <hip/hip_runtime.h>

// Per-edge dot product: score[e] = dot(h[src[e]], h[dst[e]]), D=128 f32.
// 32 lanes per edge; each lane holds one float4 of each row (fully coalesced
// 512B row reads); shfl_xor butterfly reduce within the 32-lane subgroup.

__global__ void edge_dot_kernel(const float* __restrict__ h,
                                const int* __restrict__ src,
                                const int* __restrict__ dst,
                                float* __restrict__ out,
                                int n_edges) {
    int group = (int)((blockIdx.x * (size_t)blockDim.x + threadIdx.x) >> 5);
    int lane  = threadIdx.x & 31;
    if (group >= n_edges) return;

    size_t s = (size_t)src[group];
    size_t d = (size_t)dst[group];

    const float4* rs = reinterpret_cast<const float4*>(h + s * 128);
    const float4* rd = reinterpret_cast<const float4*>(h + d * 128);

    float4 a = rs[lane];
    float4 b = rd[lane];
    float v = a.x * b.x + a.y * b.y + a.z * b.z + a.w * b.w;

    // Butterfly reduce across the 32-lane subgroup (masks < 32 stay inside it).
    v += __shfl_xor(v, 16);
    v += __shfl_xor(v, 8);
    v += __shfl_xor(v, 4);
    v += __shfl_xor(v, 2);
    v += __shfl_xor(v, 1);

    if (lane == 0) out[group] = v;
}

extern "C" void kernel_launch(void* const* d_in, const int* in_sizes, int n_in,
                              void* d_out, int out_size, void* d_ws, size_t ws_size,
                              hipStream_t stream) {
    const float* h   = (const float*)d_in[0];
    const int*   src = (const int*)d_in[1];
    const int*   dst = (const int*)d_in[2];
    float*       out = (float*)d_out;

    int n_edges = in_sizes[1];  // 600000

    const int block = 256;                       // 8 edges per block
    int grid = (n_edges * 32 + block - 1) / block;

    edge_dot_kernel<<<grid, block, 0, stream>>>(h, src, dst, out, n_edges);
}

// Round 2
// 83.088 us; speedup vs baseline: 1.0196x; 1.0196x over previous
//
#include <hip/hip_runtime.h>

// Per-edge dot product: score[e] = dot(h[src[e]], h[dst[e]]), D=128 f32.
// 32 lanes per edge-slot; each 32-lane group handles 4 edges, issuing all
// 8 row loads (float4/lane each) before reducing -> 4x the in-flight bytes
// per wave vs the 1-edge version, to cover random-gather latency.

__device__ __forceinline__ float dot_reduce32(float4 a, float4 b) {
    float v = a.x * b.x + a.y * b.y + a.z * b.z + a.w * b.w;
    v += __shfl_xor(v, 16);
    v += __shfl_xor(v, 8);
    v += __shfl_xor(v, 4);
    v += __shfl_xor(v, 2);
    v += __shfl_xor(v, 1);
    return v;
}

__global__ void edge_dot4_kernel(const float* __restrict__ h,
                                 const int* __restrict__ src,
                                 const int* __restrict__ dst,
                                 float* __restrict__ out,
                                 int n_edges) {
    const int lane = threadIdx.x & 31;
    const long long gid =
        ((long long)blockIdx.x * blockDim.x + threadIdx.x) >> 5;
    long long e0 = gid * 4;
    if (e0 >= n_edges) return;

    const float4* __restrict__ H = reinterpret_cast<const float4*>(h);

    if (e0 + 3 < (long long)n_edges) {
        // Index loads (uniform within group; L1-broadcast).
        int s0 = src[e0],     s1 = src[e0 + 1], s2 = src[e0 + 2], s3 = src[e0 + 3];
        int d0 = dst[e0],     d1 = dst[e0 + 1], d2 = dst[e0 + 2], d3 = dst[e0 + 3];

        // Issue all 8 row loads before any use (independent -> all in flight).
        float4 a0 = H[(size_t)s0 * 32 + lane];
        float4 b0 = H[(size_t)d0 * 32 + lane];
        float4 a1 = H[(size_t)s1 * 32 + lane];
        float4 b1 = H[(size_t)d1 * 32 + lane];
        float4 a2 = H[(size_t)s2 * 32 + lane];
        float4 b2 = H[(size_t)d2 * 32 + lane];
        float4 a3 = H[(size_t)s3 * 32 + lane];
        float4 b3 = H[(size_t)d3 * 32 + lane];

        float v0 = dot_reduce32(a0, b0);
        float v1 = dot_reduce32(a1, b1);
        float v2 = dot_reduce32(a2, b2);
        float v3 = dot_reduce32(a3, b3);

        if (lane == 0) {
            out[e0]     = v0;
            out[e0 + 1] = v1;
            out[e0 + 2] = v2;
            out[e0 + 3] = v3;
        }
    } else {
        // Tail: per-edge guarded loop.
        for (long long e = e0; e < (long long)n_edges; ++e) {
            int s = src[e];
            int d = dst[e];
            float4 a = H[(size_t)s * 32 + lane];
            float4 b = H[(size_t)d * 32 + lane];
            float v = dot_reduce32(a, b);
            if (lane == 0) out[e] = v;
        }
    }
}

extern "C" void kernel_launch(void* const* d_in, const int* in_sizes, int n_in,
                              void* d_out, int out_size, void* d_ws, size_t ws_size,
                              hipStream_t stream) {
    const float* h   = (const float*)d_in[0];
    const int*   src = (const int*)d_in[1];
    const int*   dst = (const int*)d_in[2];
    float*       out = (float*)d_out;

    int n_edges = in_sizes[1];  // 600000

    const int block = 256;
    long long n_groups  = ((long long)n_edges + 3) / 4;   // 4 edges per 32-lane group
    long long n_threads = n_groups * 32;
    int grid = (int)((n_threads + block - 1) / block);

    edge_dot4_kernel<<<grid, block, 0, stream>>>(h, src, dst, out, n_edges);
}